// Round 1
// baseline (429.209 us; speedup 1.0000x reference)
//
#include <hip/hip_runtime.h>
#include <hip/hip_bf16.h>

typedef float  float4v  __attribute__((ext_vector_type(4)));
typedef short  short8v  __attribute__((ext_vector_type(8)));
typedef short  short4v  __attribute__((ext_vector_type(4)));
typedef __bf16 bf16x8   __attribute__((ext_vector_type(8)));

constexpr int NB = 512, T = 64, DIN = 1024, DOUT = 1024;
constexpr int OT  = 64;       // output tile per block
constexpr int BK  = 64;       // K tile
constexpr int LDA = 72;       // padded bf16 LDS row stride (16B-aligned rows, 2-way-max bank alias)
constexpr int LDP = OT + 1;   // padded fp32 pot stride

__device__ __forceinline__ short f2bf(float x) {
    __hip_bfloat16 h = __float2bfloat16(x);   // RNE
    return __builtin_bit_cast(short, h);
}

__global__ void __launch_bounds__(256)
snn_fused_kernel(const float* __restrict__ A,     // (N,T,DIN) binary 0/1
                 const float* __restrict__ W,     // (DOUT,DIN)
                 const float* __restrict__ bias,
                 const float* __restrict__ gamma,
                 const float* __restrict__ beta,
                 const float* __restrict__ rmean,
                 const float* __restrict__ rvar,
                 float* __restrict__ out)         // spikes (N,T,DOUT) ++ counts (N,DOUT)
{
    __shared__ short As[64 * LDA];
    __shared__ short Bs[OT * LDA];
    __shared__ float potS[64 * LDP];
    __shared__ float ratioS[OT];
    __shared__ float bstepS[OT];

    const int tid   = threadIdx.x;
    const int n     = blockIdx.y;
    const int oBase = blockIdx.x * OT;

    // BN fold for this block's 64 outputs (note: no eps, matching reference)
    if (tid < OT) {
        int o = oBase + tid;
        float r = gamma[o] / sqrtf(rvar[o]);
        ratioS[tid] = r;
        bstepS[tid] = ((bias[o] - rmean[o]) * r + beta[o]) * (1.0f / 64.0f);  // b_norm / T
    }
    __syncthreads();

    const int lane = tid & 63;
    const int wave = tid >> 6;
    const int wm   = wave & 1;    // 32-row half
    const int wn   = wave >> 1;   // 32-col half
    const int l15  = lane & 15;
    const int quad = lane >> 4;
    const int srow = tid >> 4;    // staging row 0..15
    const int sf4  = tid & 15;    // staging float4 col 0..15

    float4v acc[2][2];
    #pragma unroll
    for (int mi = 0; mi < 2; mi++)
        #pragma unroll
        for (int ni = 0; ni < 2; ni++)
            #pragma unroll
            for (int k = 0; k < 4; k++) acc[mi][ni][k] = 0.f;

    const float* Ab = A + (size_t)n * (T * DIN);

    for (int kb = 0; kb < DIN; kb += BK) {
        // ---- global loads (fp32), before barrier so they overlap prior MFMA
        float4 aV[4], bV[4];
        #pragma unroll
        for (int i = 0; i < 4; i++) {
            int r = srow + 16 * i;
            aV[i] = reinterpret_cast<const float4*>(Ab + (size_t)r * DIN + kb)[sf4];
            bV[i] = reinterpret_cast<const float4*>(W + (size_t)(oBase + r) * DIN + kb)[sf4];
        }
        __syncthreads();   // prior MFMA reads of As/Bs done
        // ---- convert + store to LDS (BN ratio folded into B here)
        #pragma unroll
        for (int i = 0; i < 4; i++) {
            int r = srow + 16 * i;
            float rt = ratioS[r];
            short4v a4, b4;
            a4[0] = f2bf(aV[i].x); a4[1] = f2bf(aV[i].y);
            a4[2] = f2bf(aV[i].z); a4[3] = f2bf(aV[i].w);
            b4[0] = f2bf(bV[i].x * rt); b4[1] = f2bf(bV[i].y * rt);
            b4[2] = f2bf(bV[i].z * rt); b4[3] = f2bf(bV[i].w * rt);
            *reinterpret_cast<short4v*>(&As[r * LDA + sf4 * 4]) = a4;
            *reinterpret_cast<short4v*>(&Bs[r * LDA + sf4 * 4]) = b4;
        }
        __syncthreads();
        // ---- MFMA over the BK=64 tile (2 k-steps of 32)
        #pragma unroll
        for (int ks = 0; ks < 2; ks++) {
            int k0 = ks * 32 + quad * 8;
            bf16x8 af[2], bfv[2];
            #pragma unroll
            for (int mi = 0; mi < 2; mi++)
                af[mi] = __builtin_bit_cast(bf16x8,
                    *reinterpret_cast<const short8v*>(&As[(wm * 32 + mi * 16 + l15) * LDA + k0]));
            #pragma unroll
            for (int ni = 0; ni < 2; ni++)
                bfv[ni] = __builtin_bit_cast(bf16x8,
                    *reinterpret_cast<const short8v*>(&Bs[(wn * 32 + ni * 16 + l15) * LDA + k0]));
            #pragma unroll
            for (int mi = 0; mi < 2; mi++)
                #pragma unroll
                for (int ni = 0; ni < 2; ni++)
                    acc[mi][ni] = __builtin_amdgcn_mfma_f32_16x16x32_bf16(
                        af[mi], bfv[ni], acc[mi][ni], 0, 0, 0);
        }
    }

    // ---- epilogue: accumulators -> potS (C/D layout: col=lane&15, row=quad*4+reg)
    #pragma unroll
    for (int mi = 0; mi < 2; mi++)
        #pragma unroll
        for (int ni = 0; ni < 2; ni++)
            #pragma unroll
            for (int r = 0; r < 4; r++) {
                int row = wm * 32 + mi * 16 + quad * 4 + r;
                int col = wn * 32 + ni * 16 + l15;
                potS[row * LDP + col] = acc[mi][ni][r];
            }
    __syncthreads();

    // ---- integrate-and-fire scan over T (sequential), one thread per output col
    if (tid < OT) {
        float pot = 0.f, cnt = 0.f;
        const float bst = bstepS[tid];
        float* so = out + (size_t)n * T * DOUT + oBase + tid;
        for (int t = 0; t < T; t++) {
            pot += potS[t * LDP + tid] + bst;
            float spk = (pot >= 1.0f) ? 1.0f : 0.0f;
            pot -= spk;
            cnt += spk;
            so[(size_t)t * DOUT] = spk;
        }
        out[(size_t)NB * T * DOUT + (size_t)n * DOUT + oBase + tid] = cnt;
    }
}

extern "C" void kernel_launch(void* const* d_in, const int* in_sizes, int n_in,
                              void* d_out, int out_size, void* d_ws, size_t ws_size,
                              hipStream_t stream) {
    const float* A     = (const float*)d_in[0];  // input_feature_st
    // d_in[1] (input_features_sc) is dead code in the reference's returned outputs
    const float* W     = (const float*)d_in[2];
    const float* bias  = (const float*)d_in[3];
    const float* gamma = (const float*)d_in[4];
    const float* beta  = (const float*)d_in[5];
    const float* rmean = (const float*)d_in[6];
    const float* rvar  = (const float*)d_in[7];

    dim3 grid(DOUT / OT, NB);   // (16, 512)
    snn_fused_kernel<<<grid, 256, 0, stream>>>(A, W, bias, gamma, beta, rmean, rvar,
                                               (float*)d_out);
}

// Round 2
// 368.276 us; speedup vs baseline: 1.1655x; 1.1655x over previous
//
#include <hip/hip_runtime.h>
#include <hip/hip_bf16.h>

typedef float  float4v __attribute__((ext_vector_type(4)));
typedef short  short8v __attribute__((ext_vector_type(8)));
typedef short  short4v __attribute__((ext_vector_type(4)));
typedef __bf16 bf16x8  __attribute__((ext_vector_type(8)));
typedef float  f32x4   __attribute__((ext_vector_type(4)));

constexpr int NB = 512, T = 64, DIN = 1024, DOUT = 1024;
constexpr int BM = 128, BN = 128, BK = 64;
constexpr int LDA = 72;                    // A LDS row stride in bf16 (pad: 144 B)
constexpr int A_BYTES = BM * LDA * 2;      // 18432
constexpr int B_BYTES = BN * BK * 2;       // 16384 (unpadded, XOR-swizzled slots)
constexpr int SMEM_BYTES = A_BYTES + B_BYTES;  // 34816 >= potS 64*128*4=32768

__device__ __forceinline__ short f2bf_rne(float x) {
    return __builtin_bit_cast(short, __float2bfloat16(x));
}
// A is exactly {0.0f, 1.0f}: truncating the mantissa is exact.
__device__ __forceinline__ short f2bf_trunc(float x) {
    return (short)(__builtin_bit_cast(unsigned int, x) >> 16);
}

__device__ __forceinline__ void load_lds_16B(const void* g, void* l) {
    __builtin_amdgcn_global_load_lds(
        (const __attribute__((address_space(1))) unsigned int*)g,
        (__attribute__((address_space(3))) unsigned int*)l, 16, 0, 0);
}

// Prepass: Wn[o][k] = bf16(W[o][k] * gamma[o]/sqrt(rvar[o]))   (2 MB into d_ws)
__global__ void __launch_bounds__(256)
fold_w_kernel(const float* __restrict__ W, const float* __restrict__ gamma,
              const float* __restrict__ rvar, __hip_bfloat16* __restrict__ Wn) {
    int idx = blockIdx.x * 256 + threadIdx.x;      // float4 index, 1024*256 total
    int o = idx >> 8;                              // 256 float4 per row
    float r = gamma[o] / sqrtf(rvar[o]);
    float4v w = ((const float4v*)W)[idx];
    short4v s;
    #pragma unroll
    for (int j = 0; j < 4; j++) s[j] = f2bf_rne(w[j] * r);
    ((short4v*)Wn)[idx] = s;
}

template <bool PREFOLD>
__global__ void __launch_bounds__(256)
snn_gemm_if(const float* __restrict__ A,            // (N*T, DIN) binary
            const float* __restrict__ W,            // (DOUT, DIN) fp32 (fallback)
            const __hip_bfloat16* __restrict__ Wn,  // folded bf16 (prefold)
            const float* __restrict__ bias, const float* __restrict__ gamma,
            const float* __restrict__ beta, const float* __restrict__ rmean,
            const float* __restrict__ rvar, float* __restrict__ out) {
    __shared__ __align__(16) char smem[SMEM_BYTES];
    __shared__ float ratioS[BN];
    __shared__ float bstepS[BN];
    short* AsS  = (short*)smem;
    short* BsS  = (short*)(smem + A_BYTES);
    float* potS = (float*)smem;                    // union: valid after K loop

    const int tid   = threadIdx.x;
    const int by    = blockIdx.y;                  // sample pair: n = 2*by + {0,1}
    const int oBase = blockIdx.x * BN;

    if (tid < BN) {
        int o = oBase + tid;
        float r = gamma[o] / sqrtf(rvar[o]);
        ratioS[tid] = r;
        bstepS[tid] = ((bias[o] - rmean[o]) * r + beta[o]) * (1.0f / 64.0f);
    }
    __syncthreads();

    const int lane = tid & 63;
    const int wv   = tid >> 6;
    const int wr   = wv & 1;      // row half (64 rows)
    const int wc   = wv >> 1;     // col half (64 cols)
    const int l15  = lane & 15;
    const int quad = lane >> 4;

    f32x4 acc[4][4] = {};

    const float* Ab = A + (size_t)by * BM * DIN;

    for (int kb = 0; kb < DIN; kb += BK) {
        // ---- A global loads (fp32, 8 floats/thread/group, 4 groups) pre-barrier
        float4v av[4][2];
        #pragma unroll
        for (int i = 0; i < 4; i++) {
            int g = i * 256 + tid;                 // element-group of 8
            int r = g >> 3, k8 = g & 7;
            const float4v* p = (const float4v*)(Ab + (size_t)r * DIN + kb + k8 * 8);
            av[i][0] = p[0];
            av[i][1] = p[1];
        }
        float4v bv[4][2];
        if constexpr (!PREFOLD) {
            #pragma unroll
            for (int i = 0; i < 4; i++) {
                int slot = i * 256 + tid;
                int r = slot >> 3, k8 = (slot & 7) ^ (r & 7);
                const float4v* p = (const float4v*)(W + (size_t)(oBase + r) * DIN + kb + k8 * 8);
                bv[i][0] = p[0];
                bv[i][1] = p[1];
            }
        }
        __syncthreads();   // prior tile's MFMA reads done; LDS writable

        // ---- B: folded bf16 straight to LDS (XOR-swizzled 16B slots)
        if constexpr (PREFOLD) {
            #pragma unroll
            for (int i = 0; i < 4; i++) {
                int slot = i * 256 + tid;
                int r = slot >> 3, k8 = (slot & 7) ^ (r & 7);
                load_lds_16B(Wn + (size_t)(oBase + r) * DIN + kb + k8 * 8,
                             BsS + (size_t)slot * 8);
            }
        } else {
            #pragma unroll
            for (int i = 0; i < 4; i++) {
                int slot = i * 256 + tid;
                int r = slot >> 3;
                float rt = ratioS[r];
                short8v s;
                #pragma unroll
                for (int j = 0; j < 4; j++) {
                    s[j]     = f2bf_rne(bv[i][0][j] * rt);
                    s[j + 4] = f2bf_rne(bv[i][1][j] * rt);
                }
                *(short8v*)(BsS + (size_t)slot * 8) = s;
            }
        }
        // ---- A: exact truncate-pack to bf16, padded rows
        #pragma unroll
        for (int i = 0; i < 4; i++) {
            int g = i * 256 + tid;
            int r = g >> 3, k8 = g & 7;
            short8v s;
            #pragma unroll
            for (int j = 0; j < 4; j++) {
                s[j]     = f2bf_trunc(av[i][0][j]);
                s[j + 4] = f2bf_trunc(av[i][1][j]);
            }
            *(short8v*)(&AsS[r * LDA + k8 * 8]) = s;
        }
        __syncthreads();

        // ---- MFMA: 2 k-steps x 4x4 tiles of 16x16x32
        #pragma unroll
        for (int ks = 0; ks < 2; ks++) {
            bf16x8 af[4], bfv[4];
            #pragma unroll
            for (int mi = 0; mi < 4; mi++)
                af[mi] = __builtin_bit_cast(bf16x8,
                    *(const short8v*)(&AsS[(wr * 64 + mi * 16 + l15) * LDA + ks * 32 + quad * 8]));
            #pragma unroll
            for (int ni = 0; ni < 4; ni++) {
                int row  = wc * 64 + ni * 16 + l15;
                int slot = row * 8 + ((ks * 4 + quad) ^ (l15 & 7));
                bfv[ni] = __builtin_bit_cast(bf16x8, *(const short8v*)(BsS + (size_t)slot * 8));
            }
            #pragma unroll
            for (int mi = 0; mi < 4; mi++)
                #pragma unroll
                for (int ni = 0; ni < 4; ni++)
                    acc[mi][ni] = __builtin_amdgcn_mfma_f32_16x16x32_bf16(
                        af[mi], bfv[ni], acc[mi][ni], 0, 0, 0);
        }
    }

    __syncthreads();   // all MFMA reads of staging LDS done; potS aliases it

    // ---- two 64-row chunks: dump acc -> potS, then IF scan (t = row within chunk)
    #pragma unroll 1
    for (int s = 0; s < 2; s++) {
        if (wr == s) {
            #pragma unroll
            for (int mi = 0; mi < 4; mi++)
                #pragma unroll
                for (int ni = 0; ni < 4; ni++)
                    #pragma unroll
                    for (int r = 0; r < 4; r++)
                        potS[(mi * 16 + quad * 4 + r) * BN + wc * 64 + ni * 16 + l15] =
                            acc[mi][ni][r];
        }
        __syncthreads();
        if (tid < BN) {
            int n = by * 2 + s;
            float pot = 0.f, cnt = 0.f;
            const float bst = bstepS[tid];
            float* so = out + (size_t)n * T * DOUT + oBase + tid;
            for (int t = 0; t < T; t++) {
                pot += potS[t * BN + tid] + bst;
                float spk = (pot >= 1.0f) ? 1.0f : 0.0f;
                pot -= spk;
                cnt += spk;
                so[(size_t)t * DOUT] = spk;
            }
            out[(size_t)NB * T * DOUT + (size_t)n * DOUT + oBase + tid] = cnt;
        }
        __syncthreads();
    }
}

extern "C" void kernel_launch(void* const* d_in, const int* in_sizes, int n_in,
                              void* d_out, int out_size, void* d_ws, size_t ws_size,
                              hipStream_t stream) {
    const float* A     = (const float*)d_in[0];  // input_feature_st
    // d_in[1] (input_features_sc) feeds only the un-returned ANN path — dead.
    const float* W     = (const float*)d_in[2];
    const float* bias  = (const float*)d_in[3];
    const float* gamma = (const float*)d_in[4];
    const float* beta  = (const float*)d_in[5];
    const float* rmean = (const float*)d_in[6];
    const float* rvar  = (const float*)d_in[7];
    float* out = (float*)d_out;

    dim3 grid(DOUT / BN, NB / 2);   // (8, 256)
    const size_t wn_bytes = (size_t)DOUT * DIN * sizeof(__hip_bfloat16);  // 2 MB
    if (d_ws != nullptr && ws_size >= wn_bytes) {
        __hip_bfloat16* Wn = (__hip_bfloat16*)d_ws;
        fold_w_kernel<<<DOUT * DIN / 4 / 256, 256, 0, stream>>>(W, gamma, rvar, Wn);
        snn_gemm_if<true><<<grid, 256, 0, stream>>>(A, W, Wn, bias, gamma, beta,
                                                    rmean, rvar, out);
    } else {
        snn_gemm_if<false><<<grid, 256, 0, stream>>>(A, W, nullptr, bias, gamma, beta,
                                                     rmean, rvar, out);
    }
}

// Round 4
// 306.220 us; speedup vs baseline: 1.4016x; 1.2026x over previous
//
#include <hip/hip_runtime.h>
#include <hip/hip_bf16.h>

typedef float  float4v __attribute__((ext_vector_type(4)));
typedef short  short8v __attribute__((ext_vector_type(8)));
typedef short  short4v __attribute__((ext_vector_type(4)));
typedef __bf16 bf16x8  __attribute__((ext_vector_type(8)));
typedef float  f32x4   __attribute__((ext_vector_type(4)));

constexpr int NB = 512, T = 64, DIN = 1024, DOUT = 1024;
constexpr int BM = 128, BN = 128, BK = 64;

// ---- workspace layout (bf16-DMA path) ----
constexpr size_t ABF_BYTES = (size_t)NB * T * DIN * 2;   // 67,108,864
constexpr size_t WN_BYTES  = (size_t)DOUT * DIN * 2;     // 2,097,152
constexpr size_t WS_BF16   = ABF_BYTES + WN_BYTES;       // ~69 MB

__device__ __forceinline__ short f2bf_rne(float x) {
    return __builtin_bit_cast(short, __float2bfloat16(x));
}
__device__ __forceinline__ short f2bf_trunc(float x) {   // exact for {0,1}
    return (short)(__builtin_bit_cast(unsigned int, x) >> 16);
}
__device__ __forceinline__ void load_lds_16B(const void* g, void* l) {
    __builtin_amdgcn_global_load_lds(
        (const __attribute__((address_space(1))) unsigned int*)g,
        (__attribute__((address_space(3))) unsigned int*)l, 16, 0, 0);
}

// ---- prepass: A fp32 (binary) -> bf16 via exact truncation. 8 elems/thread.
__global__ void __launch_bounds__(256)
prep_a_kernel(const float* __restrict__ A, short* __restrict__ Abf) {
    int idx = blockIdx.x * 256 + threadIdx.x;            // 8-elem group
    const float4v* p = (const float4v*)A + (size_t)idx * 2;
    float4v v0 = __builtin_nontemporal_load(p);
    float4v v1 = __builtin_nontemporal_load(p + 1);
    short8v s;
    #pragma unroll
    for (int j = 0; j < 4; j++) {
        s[j]     = f2bf_trunc(v0[j]);
        s[j + 4] = f2bf_trunc(v1[j]);
    }
    *((short8v*)Abf + idx) = s;                          // cached: re-read soon
}

// ---- prepass: Wn = bf16(W * gamma/sqrt(rvar))
__global__ void __launch_bounds__(256)
fold_w_kernel(const float* __restrict__ W, const float* __restrict__ gamma,
              const float* __restrict__ rvar, short* __restrict__ Wn) {
    int idx = blockIdx.x * 256 + threadIdx.x;            // float4 group
    int o = idx >> 8;
    float r = gamma[o] / sqrtf(rvar[o]);
    float4v w = ((const float4v*)W)[idx];
    short4v s;
    #pragma unroll
    for (int j = 0; j < 4; j++) s[j] = f2bf_rne(w[j] * r);
    ((short4v*)Wn)[idx] = s;
}

// ---- main: bf16 GEMM (global_load_lds staging, both operands) + IF scan
__global__ void __launch_bounds__(256, 4)
snn_gemm_if_dma(const short* __restrict__ Abf,  // (N*T, DIN) bf16 {0,1}
                const short* __restrict__ Wn,   // (DOUT, DIN) bf16, BN-folded
                const float* __restrict__ bias, const float* __restrict__ gamma,
                const float* __restrict__ beta, const float* __restrict__ rmean,
                const float* __restrict__ rvar, float* __restrict__ out) {
    __shared__ __align__(16) char smem[32768];   // staging 2x16KB; potS union
    __shared__ float bstepS[BN];
    char* AsS   = smem;                          // 1024 slots x 16B
    char* BsS   = smem + 16384;
    float* potS = (float*)smem;                  // 64 x 128 fp32, quad-swizzled

    const int tid = threadIdx.x;
    const int bs  = blockIdx.x;                  // sample pair; XCD = bs % 8
    const int oB  = blockIdx.y * BN;

    if (tid < BN) {
        int o = oB + tid;
        float r = gamma[o] / sqrtf(rvar[o]);
        bstepS[tid] = ((bias[o] - rmean[o]) * r + beta[o]) * (1.0f / 64.0f);
    }

    const int lane = tid & 63;
    const int wv   = tid >> 6;
    const int wr   = wv & 1;
    const int wc   = wv >> 1;
    const int l15  = lane & 15;
    const int quad = lane >> 4;

    // staging source byte-offsets: slot s holds row=s>>3, chunk=(s&7)^(row&7)
    int srcOff[4];
    #pragma unroll
    for (int i = 0; i < 4; i++) {
        int s   = i * 256 + tid;
        int row = s >> 3;
        int ck  = (s & 7) ^ (row & 7);
        srcOff[i] = (row * DIN + ck * 8) * 2;    // bytes
    }
    // fragment LDS byte-offsets: row r, chunk c -> slot r*8 + (c^(r&7))
    int aOff[4][2], bOff[4][2];
    #pragma unroll
    for (int i = 0; i < 4; i++) {
        int ra = wr * 64 + i * 16 + l15;
        int rb = wc * 64 + i * 16 + l15;
        #pragma unroll
        for (int ks = 0; ks < 2; ks++) {
            int c = ks * 4 + quad;
            aOff[i][ks] = (ra * 8 + (c ^ (ra & 7))) * 16;
            bOff[i][ks] = (rb * 8 + (c ^ (rb & 7))) * 16;
        }
    }

    f32x4 acc[4][4] = {};
    const char* Ab = (const char*)(Abf + (size_t)bs * BM * DIN);
    const char* Bb = (const char*)(Wn + (size_t)oB * DIN);

    for (int kb = 0; kb < DIN; kb += BK) {
        __syncthreads();                         // prev tile ds_reads done
        const int kbB = kb * 2;
        #pragma unroll
        for (int i = 0; i < 4; i++) {
            int s = i * 256 + tid;
            load_lds_16B(Ab + srcOff[i] + kbB, AsS + s * 16);
            load_lds_16B(Bb + srcOff[i] + kbB, BsS + s * 16);
        }
        __syncthreads();                         // staged data visible

        #pragma unroll
        for (int ks = 0; ks < 2; ks++) {
            bf16x8 af[4], bf[4];
            #pragma unroll
            for (int i = 0; i < 4; i++)
                af[i] = __builtin_bit_cast(bf16x8, *(const short8v*)(AsS + aOff[i][ks]));
            #pragma unroll
            for (int i = 0; i < 4; i++)
                bf[i] = __builtin_bit_cast(bf16x8, *(const short8v*)(BsS + bOff[i][ks]));
            #pragma unroll
            for (int mi = 0; mi < 4; mi++)
                #pragma unroll
                for (int ni = 0; ni < 4; ni++)
                    acc[mi][ni] = __builtin_amdgcn_mfma_f32_16x16x32_bf16(
                        af[mi], bf[ni], acc[mi][ni], 0, 0, 0);
        }
    }

    __syncthreads();                             // staging free; potS aliases it

    // two 64-row chunks: acc -> potS (quad-swizzled banks), then IF scan
    #pragma unroll 1
    for (int s = 0; s < 2; s++) {
        if (wr == s) {
            #pragma unroll
            for (int mi = 0; mi < 4; mi++)
                #pragma unroll
                for (int ni = 0; ni < 4; ni++)
                    #pragma unroll
                    for (int r = 0; r < 4; r++) {
                        int row = mi * 16 + quad * 4 + r;
                        int col = (wc * 64 + ni * 16 + l15) ^ (quad << 3);
                        potS[row * BN + col] = acc[mi][ni][r];
                    }
        }
        __syncthreads();
        if (tid < BN) {
            int n = bs * 2 + s;
            float pot = 0.f, cnt = 0.f;
            const float bst = bstepS[tid];
            float* so = out + (size_t)n * T * DOUT + oB + tid;
            for (int t = 0; t < T; t++) {
                pot += potS[t * BN + (tid ^ (((t >> 2) & 3) << 3))] + bst;
                float spk = (pot >= 1.0f) ? 1.0f : 0.0f;
                pot -= spk;
                cnt += spk;
                __builtin_nontemporal_store(spk, so + (size_t)t * DOUT);
            }
            __builtin_nontemporal_store(
                cnt, out + (size_t)NB * T * DOUT + (size_t)n * DOUT + oB + tid);
        }
        __syncthreads();
    }
}

// ===================== fallback (round-2 proven path) =====================

constexpr int LDA_F = 72;
constexpr int A_BYTES_F = BM * LDA_F * 2;
constexpr int SMEM_F = A_BYTES_F + BN * BK * 2;

template <bool PREFOLD>
__global__ void __launch_bounds__(256)
snn_gemm_if(const float* __restrict__ A, const float* __restrict__ W,
            const short* __restrict__ Wn,
            const float* __restrict__ bias, const float* __restrict__ gamma,
            const float* __restrict__ beta, const float* __restrict__ rmean,
            const float* __restrict__ rvar, float* __restrict__ out) {
    __shared__ __align__(16) char smem[SMEM_F];
    __shared__ float ratioS[BN];
    __shared__ float bstepS[BN];
    short* AsS  = (short*)smem;
    short* BsS  = (short*)(smem + A_BYTES_F);
    float* potS = (float*)smem;

    const int tid   = threadIdx.x;
    const int by    = blockIdx.y;
    const int oBase = blockIdx.x * BN;

    if (tid < BN) {
        int o = oBase + tid;
        float r = gamma[o] / sqrtf(rvar[o]);
        ratioS[tid] = r;
        bstepS[tid] = ((bias[o] - rmean[o]) * r + beta[o]) * (1.0f / 64.0f);
    }
    __syncthreads();

    const int lane = tid & 63;
    const int wv   = tid >> 6;
    const int wr   = wv & 1;
    const int wc   = wv >> 1;
    const int l15  = lane & 15;
    const int quad = lane >> 4;

    f32x4 acc[4][4] = {};
    const float* Ab = A + (size_t)by * BM * DIN;

    for (int kb = 0; kb < DIN; kb += BK) {
        float4v av[4][2];
        #pragma unroll
        for (int i = 0; i < 4; i++) {
            int g = i * 256 + tid;
            int r = g >> 3, k8 = g & 7;
            const float4v* p = (const float4v*)(Ab + (size_t)r * DIN + kb + k8 * 8);
            av[i][0] = p[0];
            av[i][1] = p[1];
        }
        float4v bv[4][2];
        if constexpr (!PREFOLD) {
            #pragma unroll
            for (int i = 0; i < 4; i++) {
                int slot = i * 256 + tid;
                int r = slot >> 3, k8 = (slot & 7) ^ (r & 7);
                const float4v* p = (const float4v*)(W + (size_t)(oBase + r) * DIN + kb + k8 * 8);
                bv[i][0] = p[0];
                bv[i][1] = p[1];
            }
        }
        __syncthreads();

        if constexpr (PREFOLD) {
            #pragma unroll
            for (int i = 0; i < 4; i++) {
                int slot = i * 256 + tid;
                int r = slot >> 3, k8 = (slot & 7) ^ (r & 7);
                load_lds_16B(Wn + (size_t)(oBase + r) * DIN + kb + k8 * 8,
                             BsS + (size_t)slot * 8);
            }
        } else {
            #pragma unroll
            for (int i = 0; i < 4; i++) {
                int slot = i * 256 + tid;
                int r = slot >> 3;
                float rt = ratioS[r];
                short8v s;
                #pragma unroll
                for (int j = 0; j < 4; j++) {
                    s[j]     = f2bf_rne(bv[i][0][j] * rt);
                    s[j + 4] = f2bf_rne(bv[i][1][j] * rt);
                }
                *(short8v*)(BsS + (size_t)slot * 8) = s;
            }
        }
        #pragma unroll
        for (int i = 0; i < 4; i++) {
            int g = i * 256 + tid;
            int r = g >> 3, k8 = g & 7;
            short8v s;
            #pragma unroll
            for (int j = 0; j < 4; j++) {
                s[j]     = f2bf_trunc(av[i][0][j]);
                s[j + 4] = f2bf_trunc(av[i][1][j]);
            }
            *(short8v*)(&AsS[r * LDA_F + k8 * 8]) = s;
        }
        __syncthreads();

        #pragma unroll
        for (int ks = 0; ks < 2; ks++) {
            bf16x8 af[4], bfv[4];
            #pragma unroll
            for (int mi = 0; mi < 4; mi++)
                af[mi] = __builtin_bit_cast(bf16x8,
                    *(const short8v*)(&AsS[(wr * 64 + mi * 16 + l15) * LDA_F + ks * 32 + quad * 8]));
            #pragma unroll
            for (int ni = 0; ni < 4; ni++) {
                int row  = wc * 64 + ni * 16 + l15;
                int slot = row * 8 + ((ks * 4 + quad) ^ (l15 & 7));
                bfv[ni] = __builtin_bit_cast(bf16x8, *(const short8v*)(BsS + (size_t)slot * 8));
            }
            #pragma unroll
            for (int mi = 0; mi < 4; mi++)
                #pragma unroll
                for (int ni = 0; ni < 4; ni++)
                    acc[mi][ni] = __builtin_amdgcn_mfma_f32_16x16x32_bf16(
                        af[mi], bfv[ni], acc[mi][ni], 0, 0, 0);
        }
    }

    __syncthreads();

    #pragma unroll 1
    for (int s = 0; s < 2; s++) {
        if (wr == s) {
            #pragma unroll
            for (int mi = 0; mi < 4; mi++)
                #pragma unroll
                for (int ni = 0; ni < 4; ni++)
                    #pragma unroll
                    for (int r = 0; r < 4; r++)
                        potS[(mi * 16 + quad * 4 + r) * BN + wc * 64 + ni * 16 + l15] =
                            acc[mi][ni][r];
        }
        __syncthreads();
        if (tid < BN) {
            int n = by * 2 + s;
            float pot = 0.f, cnt = 0.f;
            const float bst = bstepS[tid];
            float* so = out + (size_t)n * T * DOUT + oBase + tid;
            for (int t = 0; t < T; t++) {
                pot += potS[t * BN + tid] + bst;
                float spk = (pot >= 1.0f) ? 1.0f : 0.0f;
                pot -= spk;
                cnt += spk;
                so[(size_t)t * DOUT] = spk;
            }
            out[(size_t)NB * T * DOUT + (size_t)n * DOUT + oBase + tid] = cnt;
        }
        __syncthreads();
    }
}

extern "C" void kernel_launch(void* const* d_in, const int* in_sizes, int n_in,
                              void* d_out, int out_size, void* d_ws, size_t ws_size,
                              hipStream_t stream) {
    const float* A     = (const float*)d_in[0];
    // d_in[1] (input_features_sc) feeds only the un-returned ANN path — dead.
    const float* W     = (const float*)d_in[2];
    const float* bias  = (const float*)d_in[3];
    const float* gamma = (const float*)d_in[4];
    const float* beta  = (const float*)d_in[5];
    const float* rmean = (const float*)d_in[6];
    const float* rvar  = (const float*)d_in[7];
    float* out = (float*)d_out;

    if (d_ws != nullptr && ws_size >= WS_BF16) {
        short* Abf = (short*)d_ws;
        short* Wn  = (short*)((char*)d_ws + ABF_BYTES);
        prep_a_kernel<<<(NB * T * DIN) / 8 / 256, 256, 0, stream>>>(A, Abf);
        fold_w_kernel<<<DOUT * DIN / 4 / 256, 256, 0, stream>>>(W, gamma, rvar, Wn);
        dim3 grid(NB / 2, DOUT / BN);   // (256, 8): same-sample blocks -> same XCD
        snn_gemm_if_dma<<<grid, 256, 0, stream>>>(Abf, Wn, bias, gamma, beta,
                                                  rmean, rvar, out);
    } else if (d_ws != nullptr && ws_size >= WN_BYTES) {
        short* Wn = (short*)d_ws;
        fold_w_kernel<<<DOUT * DIN / 4 / 256, 256, 0, stream>>>(W, gamma, rvar, Wn);
        dim3 grid(DOUT / BN, NB / 2);
        snn_gemm_if<true><<<grid, 256, 0, stream>>>(A, W, Wn, bias, gamma, beta,
                                                    rmean, rvar, out);
    } else {
        dim3 grid(DOUT / BN, NB / 2);
        snn_gemm_if<false><<<grid, 256, 0, stream>>>(A, W, nullptr, bias, gamma, beta,
                                                     rmean, rvar, out);
    }
}